// Round 1
// baseline (938.037 us; speedup 1.0000x reference)
//
#include <hip/hip_runtime.h>
#include <math.h>

#define N_    16
#define C_    256
#define H_    56
#define W_    56
#define HW_   3136          // H_*W_
#define NPIX  50176         // N_*HW_
#define OUTC  512
#define SPAN_ 2304          // C_*9
#define AOC   8             // oc per block in conv kernel

__device__ __forceinline__ int bucketf(float v, float b) {
    int idx = (int)floorf((v + b) / 2.5f);
    int r = idx % 8;                 // C % matches jnp.fmod sign (dividend)
    return r < 0 ? -r : r;
}

// ---- Kernel A: bucket of each kernel row ------------------------------------
__global__ void kbucket_kernel(const float* __restrict__ kern,
                               const float* __restrict__ ah,
                               const float* __restrict__ bh,
                               int* __restrict__ kbuck) {
    int oc = blockIdx.x;
    const float* kr = kern + (size_t)oc * SPAN_;
    float dot = 0.f, ss = 0.f;
    for (int j = threadIdx.x; j < SPAN_; j += 64) {
        float kv = kr[j];
        dot += kv * ah[j];
        ss  += kv * kv;
    }
    for (int o = 32; o; o >>= 1) {
        dot += __shfl_down(dot, o);
        ss  += __shfl_down(ss, o);
    }
    if (threadIdx.x == 0) {
        float nrm = sqrtf(ss);
        float n2 = nrm * nrm;
        float n4 = n2 * n2;
        float n8 = n4 * n4;
        float v = dot + n2 * ah[SPAN_] + n4 * ah[SPAN_ + 1] + n8 * ah[SPAN_ + 2];
        kbuck[oc] = bucketf(v, bh[0]);
    }
}

// ---- Kernel B1: channel-reduced tap maps g[9][NPIX] and sumsq map s2[NPIX] --
__global__ __launch_bounds__(256) void gmaps_kernel(const float* __restrict__ x,
                                                    const float* __restrict__ ah,
                                                    float* __restrict__ g,
                                                    float* __restrict__ s2) {
    __shared__ float aL[SPAN_];
    for (int j = threadIdx.x; j < SPAN_; j += 256) aL[j] = ah[j];
    __syncthreads();
    int q = blockIdx.x * 256 + threadIdx.x;      // pixel id (n,h,w)
    int n = q / HW_;
    int p = q - n * HW_;
    const float* xb = x + (size_t)n * C_ * HW_ + p;
    float acc[9];
#pragma unroll
    for (int kk = 0; kk < 9; ++kk) acc[kk] = 0.f;
    float ssum = 0.f;
    for (int c = 0; c < C_; ++c) {
        float xv = xb[(size_t)c * HW_];
        ssum += xv * xv;
        const float* ac = &aL[c * 9];
#pragma unroll
        for (int kk = 0; kk < 9; ++kk) acc[kk] += ac[kk] * xv;
    }
#pragma unroll
    for (int kk = 0; kk < 9; ++kk) g[(size_t)kk * NPIX + q] = acc[kk];
    s2[q] = ssum;
}

// ---- Kernel B2: per-column vote -> histogram --------------------------------
__global__ __launch_bounds__(256) void vote_kernel(const float* __restrict__ g,
                                                   const float* __restrict__ s2,
                                                   const float* __restrict__ ah,
                                                   const float* __restrict__ bh,
                                                   int* __restrict__ counts) {
    __shared__ int hist[8];
    if (threadIdx.x < 8) hist[threadIdx.x] = 0;
    __syncthreads();
    int q = blockIdx.x * 256 + threadIdx.x;
    int n = q / HW_;
    int p = q - n * HW_;
    int h = p / W_;
    int w = p - h * W_;
    float dot = 0.f, ss = 0.f;
#pragma unroll
    for (int kk = 0; kk < 9; ++kk) {
        int dh = kk / 3 - 1, dw = kk % 3 - 1;
        int hh = h + dh, ww = w + dw;
        if (hh >= 0 && hh < H_ && ww >= 0 && ww < W_) {
            int idx = n * HW_ + hh * W_ + ww;
            dot += g[(size_t)kk * NPIX + idx];
            ss  += s2[idx];
        }
    }
    float qext = 0.5f * (ah[SPAN_] + ah[SPAN_ + 1] + ah[SPAN_ + 2]);
    float v = dot / sqrtf(ss) + qext;
    int b = bucketf(v, bh[0]);
    atomicAdd(&hist[b], 1);
    __syncthreads();
    if (threadIdx.x < 8) atomicAdd(&counts[threadIdx.x], hist[threadIdx.x]);
}

// ---- Kernel C: argmax bucket, build rows list, emit rows output -------------
__global__ void select_kernel(const int* __restrict__ counts,
                              const int* __restrict__ kbuck,
                              int* __restrict__ rowsb,
                              int* __restrict__ meta,
                              float* __restrict__ out, int oc_total) {
    if (threadIdx.x != 0 || blockIdx.x != 0) return;
    int best = 0, bc = counts[0];
    for (int t = 1; t < 8; ++t) {
        int c = counts[t];
        if (c > bc) { bc = c; best = t; }     // first max wins (strict >)
    }
    int cnt = 0;
    for (int oc = 0; oc < OUTC; ++oc)
        if (kbuck[oc] == best) rowsb[cnt++] = oc;
    meta[0] = cnt;
    if (cnt == 0) {
        for (int oc = 0; oc < OUTC; ++oc) rowsb[oc] = oc;   // use-all path
    } else {
        for (int i = cnt; i < OUTC; ++i) rowsb[i] = 0;      // safety fill
    }
    // rows section of d_out: after 16*oc_total*3136 floats; written as exact
    // integer-valued floats (harness reads the whole buffer as f32).
    int nw = cnt < oc_total ? cnt : oc_total;
    float* rout = out + (size_t)N_ * oc_total * HW_;
    for (int i = 0; i < nw; ++i) rout[i] = (float)rowsb[i];
}

// ---- Kernel D: conv with active rows ----------------------------------------
__global__ __launch_bounds__(256) void conv_kernel(const float* __restrict__ x,
                                                   const float* __restrict__ kern,
                                                   const int* __restrict__ rowsb,
                                                   const int* __restrict__ meta,
                                                   const int* __restrict__ mode,
                                                   float* __restrict__ out,
                                                   int oc_total) {
    __shared__ __align__(16) float wLds[9 * 64 * AOC];   // [kk][cc][a], 18 KiB
    int q = blockIdx.x * 256 + threadIdx.x;
    int n = q / HW_;
    int p = q - n * HW_;
    int h = p / W_;
    int w = p - h * W_;
    int ocBase = blockIdx.y * AOC;
    float acc[AOC];
#pragma unroll
    for (int a = 0; a < AOC; ++a) acc[a] = 0.f;

    for (int c0 = 0; c0 < C_; c0 += 64) {
        // cooperative stage of 8 weight rows, 64 channels, 9 taps (transposed)
        for (int e = threadIdx.x; e < 9 * 64 * AOC; e += 256) {
            int a  = e & (AOC - 1);
            int cc = (e >> 3) & 63;
            int kk = e >> 9;
            float wv = 0.f;
            int oci = ocBase + a;
            if (oci < oc_total) {
                int row = rowsb[oci];
                wv = kern[(size_t)row * SPAN_ + (size_t)(c0 + cc) * 9 + kk];
            }
            wLds[e] = wv;
        }
        __syncthreads();
#pragma unroll
        for (int kk = 0; kk < 9; ++kk) {
            int dh = kk / 3 - 1, dw = kk % 3 - 1;
            int hh = h + dh, ww = w + dw;
            bool valid = (hh >= 0) & (hh < H_) & (ww >= 0) & (ww < W_);
            const float* xb = x + ((size_t)(n * C_ + c0) * HW_) + hh * W_ + ww;
            const float4* wp = (const float4*)&wLds[kk * 64 * AOC];
            for (int cc = 0; cc < 64; ++cc) {
                float xv = valid ? xb[(size_t)cc * HW_] : 0.f;
                float4 wa = wp[cc * 2];
                float4 wb = wp[cc * 2 + 1];
                acc[0] += wa.x * xv; acc[1] += wa.y * xv;
                acc[2] += wa.z * xv; acc[3] += wa.w * xv;
                acc[4] += wb.x * xv; acc[5] += wb.y * xv;
                acc[6] += wb.z * xv; acc[7] += wb.w * xv;
            }
        }
        __syncthreads();
    }
    int cnt = meta[0];
    float dv = 1.0f;
    if (mode[0] && cnt > 0) dv = (float)cnt / 512.0f;   // ref: out / (cnt/512)
#pragma unroll
    for (int a = 0; a < AOC; ++a) {
        int oci = ocBase + a;
        if (oci < oc_total)
            out[((size_t)n * oc_total + oci) * HW_ + p] = acc[a] / dv;
    }
}

extern "C" void kernel_launch(void* const* d_in, const int* in_sizes, int n_in,
                              void* d_out, int out_size, void* d_ws, size_t ws_size,
                              hipStream_t stream) {
    const float* x    = (const float*)d_in[0];
    const float* kern = (const float*)d_in[1];
    const float* ah   = (const float*)d_in[2];
    const float* bh   = (const float*)d_in[3];
    const int*   mode = (const int*)d_in[4];
    float* out = (float*)d_out;

    // workspace layout
    float* g      = (float*)d_ws;                       // 9*NPIX
    float* s2     = g + (size_t)9 * NPIX;               // NPIX
    int*   counts = (int*)(g + (size_t)10 * NPIX);      // 8
    int*   kbuck  = counts + 8;                         // 512
    int*   rowsb  = kbuck + OUTC;                       // 512
    int*   meta   = rowsb + OUTC;                       // 2

    // oc is data-dependent but recoverable from out_size: oc*(16*3136+1)
    int oc_total = (out_size % (N_ * HW_ + 1) == 0) ? out_size / (N_ * HW_ + 1)
                                                    : OUTC;

    hipMemsetAsync(counts, 0, 8 * sizeof(int), stream);

    kbucket_kernel<<<OUTC, 64, 0, stream>>>(kern, ah, bh, kbuck);
    gmaps_kernel<<<NPIX / 256, 256, 0, stream>>>(x, ah, g, s2);
    vote_kernel<<<NPIX / 256, 256, 0, stream>>>(g, s2, ah, bh, counts);
    select_kernel<<<1, 1, 0, stream>>>(counts, kbuck, rowsb, meta, out, oc_total);

    dim3 gridD(NPIX / 256, (oc_total + AOC - 1) / AOC);
    conv_kernel<<<gridD, 256, 0, stream>>>(x, kern, rowsb, meta, mode, out,
                                           oc_total);
}

// Round 2
// 320.210 us; speedup vs baseline: 2.9294x; 2.9294x over previous
//
#include <hip/hip_runtime.h>
#include <math.h>

#define N_    16
#define C_    256
#define H_    56
#define W_    56
#define HW_   3136          // H_*W_
#define NPIX  50176         // N_*HW_
#define OUTC  512
#define SPAN_ 2304          // C_*9

typedef unsigned short u16;
typedef unsigned int   u32;
typedef __attribute__((ext_vector_type(8))) short bf16x8;
typedef __attribute__((ext_vector_type(4))) float f32x4;
typedef __attribute__((ext_vector_type(4))) unsigned short u16x4;

__device__ __forceinline__ u16 f2bf(float v) {
    u32 x = __float_as_uint(v);
    u32 r = (x + 0x7fffu + ((x >> 16) & 1u)) >> 16;   // RNE
    return (u16)r;
}

__device__ __forceinline__ int bucketf(float v, float b) {
    int idx = (int)floorf((v + b) / 2.5f);
    int r = idx % 8;
    return r < 0 ? -r : r;
}

// ---- Kernel A: bucket of each kernel row ------------------------------------
__global__ void kbucket_kernel(const float* __restrict__ kern,
                               const float* __restrict__ ah,
                               const float* __restrict__ bh,
                               int* __restrict__ kbuck) {
    int oc = blockIdx.x;
    const float* kr = kern + (size_t)oc * SPAN_;
    float dot = 0.f, ss = 0.f;
    for (int j = threadIdx.x; j < SPAN_; j += 64) {
        float kv = kr[j];
        dot += kv * ah[j];
        ss  += kv * kv;
    }
    for (int o = 32; o; o >>= 1) {
        dot += __shfl_down(dot, o);
        ss  += __shfl_down(ss, o);
    }
    if (threadIdx.x == 0) {
        float n2 = ss;            // ||k||^2
        float n4 = n2 * n2;
        float n8 = n4 * n4;
        float v = dot + n2 * ah[SPAN_] + n4 * ah[SPAN_ + 1] + n8 * ah[SPAN_ + 2];
        kbuck[oc] = bucketf(v, bh[0]);
    }
}

// ---- Kernel B1: channel-reduced tap maps g[9][NPIX] and sumsq map s2[NPIX] --
__global__ __launch_bounds__(256) void gmaps_kernel(const float* __restrict__ x,
                                                    const float* __restrict__ ah,
                                                    float* __restrict__ g,
                                                    float* __restrict__ s2) {
    __shared__ float aL[SPAN_];
    for (int j = threadIdx.x; j < SPAN_; j += 256) aL[j] = ah[j];
    __syncthreads();
    int q = blockIdx.x * 256 + threadIdx.x;
    int n = q / HW_;
    int p = q - n * HW_;
    const float* xb = x + (size_t)n * C_ * HW_ + p;
    float acc[9];
#pragma unroll
    for (int kk = 0; kk < 9; ++kk) acc[kk] = 0.f;
    float ssum = 0.f;
    for (int c = 0; c < C_; ++c) {
        float xv = xb[(size_t)c * HW_];
        ssum += xv * xv;
        const float* ac = &aL[c * 9];
#pragma unroll
        for (int kk = 0; kk < 9; ++kk) acc[kk] += ac[kk] * xv;
    }
#pragma unroll
    for (int kk = 0; kk < 9; ++kk) g[(size_t)kk * NPIX + q] = acc[kk];
    s2[q] = ssum;
}

// ---- Kernel B2: per-column vote -> histogram --------------------------------
__global__ __launch_bounds__(256) void vote_kernel(const float* __restrict__ g,
                                                   const float* __restrict__ s2,
                                                   const float* __restrict__ ah,
                                                   const float* __restrict__ bh,
                                                   int* __restrict__ counts) {
    __shared__ int hist[8];
    if (threadIdx.x < 8) hist[threadIdx.x] = 0;
    __syncthreads();
    int q = blockIdx.x * 256 + threadIdx.x;
    int n = q / HW_;
    int p = q - n * HW_;
    int h = p / W_;
    int w = p - h * W_;
    float dot = 0.f, ss = 0.f;
#pragma unroll
    for (int kk = 0; kk < 9; ++kk) {
        int dh = kk / 3 - 1, dw = kk % 3 - 1;
        int hh = h + dh, ww = w + dw;
        if (hh >= 0 && hh < H_ && ww >= 0 && ww < W_) {
            int idx = n * HW_ + hh * W_ + ww;
            dot += g[(size_t)kk * NPIX + idx];
            ss  += s2[idx];
        }
    }
    float qext = 0.5f * (ah[SPAN_] + ah[SPAN_ + 1] + ah[SPAN_ + 2]);
    float v = dot / sqrtf(ss) + qext;
    int b = bucketf(v, bh[0]);
    atomicAdd(&hist[b], 1);
    __syncthreads();
    if (threadIdx.x < 8) atomicAdd(&counts[threadIdx.x], hist[threadIdx.x]);
}

// ---- Kernel C: argmax bucket, build rows list, emit rows output -------------
__global__ void select_kernel(const int* __restrict__ counts,
                              const int* __restrict__ kbuck,
                              int* __restrict__ rowsb,
                              int* __restrict__ meta,
                              float* __restrict__ out, int oc_total) {
    if (threadIdx.x != 0 || blockIdx.x != 0) return;
    int best = 0, bc = counts[0];
    for (int t = 1; t < 8; ++t) {
        int c = counts[t];
        if (c > bc) { bc = c; best = t; }
    }
    int cnt = 0;
    for (int oc = 0; oc < OUTC; ++oc)
        if (kbuck[oc] == best) rowsb[cnt++] = oc;
    meta[0] = cnt;
    meta[1] = (cnt == 0) ? OUTC : cnt;
    if (cnt == 0) {
        for (int oc = 0; oc < OUTC; ++oc) rowsb[oc] = oc;
    } else {
        for (int i = cnt; i < OUTC; ++i) rowsb[i] = 0;
    }
    int nw = (cnt == 0 ? OUTC : cnt);
    if (nw > oc_total) nw = oc_total;
    float* rout = out + (size_t)N_ * oc_total * HW_;
    for (int i = 0; i < nw; ++i) rout[i] = (float)rowsb[i];
}

// ---- Kernel P1: NCHW f32 -> NHWC bf16 ---------------------------------------
// grid (NPIX/64, C/64), block 256
__global__ __launch_bounds__(256) void prep_x(const float* __restrict__ x,
                                              u16* __restrict__ xp) {
    __shared__ u16 tl[64][68];           // [px][c], row stride 136B (8B aligned)
    int t = threadIdx.x;
    int px0 = blockIdx.x * 64;           // 3136 % 64 == 0 -> single image
    int c0  = blockIdx.y * 64;
    int img = px0 / HW_;
    int hw0 = px0 - img * HW_;
    int px_l = t & 63;
    int cq   = t >> 6;                   // 0..3
#pragma unroll
    for (int rep = 0; rep < 16; ++rep) {
        int c_l = rep * 4 + cq;
        float v = x[((size_t)(img * C_ + c0 + c_l)) * HW_ + hw0 + px_l];
        tl[px_l][c_l] = f2bf(v);
    }
    __syncthreads();
    int c4  = t & 15;                    // 16 * 4 channels
    int pxs = t >> 4;                    // 0..15
#pragma unroll
    for (int rep = 0; rep < 4; ++rep) {
        int pl = rep * 16 + pxs;
        u16x4 v = *(const u16x4*)(&tl[pl][c4 * 4]);
        *(u16x4*)(&xp[((size_t)(px0 + pl)) * C_ + c0 + c4 * 4]) = v;
    }
}

// ---- Kernel P2: gather active rows -> MFMA B-fragment order bf16 -------------
// wfrag element offset ((s*nfTot + g)*64 + lane)*8 ; K order = kk*256 + c
__global__ __launch_bounds__(256) void prep_w(const float* __restrict__ kern,
                                              const int* __restrict__ rowsb,
                                              const int* __restrict__ meta,
                                              const int* __restrict__ mode,
                                              u16* __restrict__ wfrag, int nfTot) {
    int e = blockIdx.x * 256 + threadIdx.x;
    int lane = e & 63;
    int t2 = e >> 6;
    int g = t2 % nfTot;
    int s = t2 / nfTot;                  // 0..71
    int kk = s >> 3;
    int cb = s & 7;
    int q = lane >> 4;
    int mcol = lane & 15;
    int ocEff = meta[1];
    int cnt = meta[0];
    float scale = (mode[0] && cnt > 0) ? 512.0f / (float)cnt : 1.0f;
    int oc_i = g * 16 + mcol;
    bool valid = oc_i < ocEff;
    int row = valid ? rowsb[oc_i] : 0;
    const float* kr = kern + (size_t)row * SPAN_;
    u16 w8[8];
#pragma unroll
    for (int j = 0; j < 8; ++j) {
        int c = cb * 32 + q * 8 + j;
        float v = valid ? kr[c * 9 + kk] * scale : 0.f;
        w8[j] = f2bf(v);
    }
    u16* dst = wfrag + ((size_t)((s * nfTot + g) * 64 + lane)) * 8;
#pragma unroll
    for (int j = 0; j < 8; ++j) dst[j] = w8[j];
}

// ---- Kernel D: MFMA implicit-GEMM conv --------------------------------------
// 1 wave/block; wave tile = 64 px x 144 oc (4 x 9 fragments of 16x16x32 bf16)
__global__ __launch_bounds__(64) void conv_mfma(const u16* __restrict__ xp,
                                                const u16* __restrict__ wfrag,
                                                float* __restrict__ out,
                                                int nfTot, int oc_total) {
    const int lane = threadIdx.x;
    const int pb = blockIdx.x * 64;
    const int fb = blockIdx.y * 9;
    int ng = nfTot - fb; if (ng > 9) ng = 9;

    int hA[4], wA[4];
    const u16* xpf[4];
#pragma unroll
    for (int f = 0; f < 4; ++f) {
        int p = pb + f * 16 + (lane & 15);
        int img = p / HW_;
        int rp = p - img * HW_;
        hA[f] = rp / W_;
        wA[f] = rp - hA[f] * W_;
        xpf[f] = xp + (size_t)p * C_ + ((lane >> 4) * 8);
    }

    f32x4 acc[4][9];
#pragma unroll
    for (int f = 0; f < 4; ++f)
#pragma unroll
        for (int g = 0; g < 9; ++g) acc[f][g] = (f32x4){0.f, 0.f, 0.f, 0.f};

    const bf16x8 zf = {0, 0, 0, 0, 0, 0, 0, 0};

    for (int kk = 0; kk < 9; ++kk) {
        const int dh = kk / 3 - 1, dw = kk % 3 - 1;
        const int offp = (dh * W_ + dw) * C_;
        bool val[4];
#pragma unroll
        for (int f = 0; f < 4; ++f) {
            int hh = hA[f] + dh, ww = wA[f] + dw;
            val[f] = (hh >= 0) & (hh < H_) & (ww >= 0) & (ww < W_);
        }
#pragma unroll
        for (int cb = 0; cb < 8; ++cb) {
            const int s = kk * 8 + cb;
            const u16* wb = wfrag + ((size_t)((s * nfTot + fb) * 64 + lane)) * 8;
            bf16x8 aX[4];
#pragma unroll
            for (int f = 0; f < 4; ++f) {
                bf16x8 a = zf;
                if (val[f]) a = *(const bf16x8*)(xpf[f] + offp + cb * 32);
                aX[f] = a;
            }
#pragma unroll
            for (int g = 0; g < 9; ++g) {
                if (g < ng) {
                    bf16x8 bW = *(const bf16x8*)(wb + (size_t)g * 64 * 8);
#pragma unroll
                    for (int f = 0; f < 4; ++f)
                        acc[f][g] = __builtin_amdgcn_mfma_f32_16x16x32_bf16(
                            aX[f], bW, acc[f][g], 0, 0, 0);
                }
            }
        }
    }

    // epilogue: D row = (lane>>4)*4 + r (pixel), col = lane&15 (oc)
#pragma unroll
    for (int f = 0; f < 4; ++f) {
        int p0 = pb + f * 16 + (lane >> 4) * 4;
        int img = p0 / HW_;
        int hw = p0 - img * HW_;
#pragma unroll
        for (int g = 0; g < 9; ++g) {
            if (g < ng) {
                int oc = (fb + g) * 16 + (lane & 15);
                if (oc < oc_total) {
                    float* op = out + ((size_t)img * oc_total + oc) * HW_ + hw;
                    *(f32x4*)op = acc[f][g];
                }
            }
        }
    }
}

extern "C" void kernel_launch(void* const* d_in, const int* in_sizes, int n_in,
                              void* d_out, int out_size, void* d_ws, size_t ws_size,
                              hipStream_t stream) {
    const float* x    = (const float*)d_in[0];
    const float* kern = (const float*)d_in[1];
    const float* ah   = (const float*)d_in[2];
    const float* bh   = (const float*)d_in[3];
    const int*   mode = (const int*)d_in[4];
    float* out = (float*)d_out;

    // oc is data-dependent but recoverable from out_size: oc*(16*3136+1)
    int oc_total = (out_size % (N_ * HW_ + 1) == 0) ? out_size / (N_ * HW_ + 1)
                                                    : OUTC;
    int nfTot = (oc_total + 15) / 16;

    // workspace layout
    u16*   xp     = (u16*)d_ws;                                  // NPIX*256
    u16*   wfrag  = xp + (size_t)NPIX * C_;                      // 72*nfTot*64*8
    float* g      = (float*)(wfrag + (size_t)72 * 32 * 64 * 8);  // 9*NPIX
    float* s2     = g + (size_t)9 * NPIX;                        // NPIX
    int*   counts = (int*)(s2 + NPIX);                           // 8
    int*   kbuck  = counts + 8;                                  // 512
    int*   rowsb  = kbuck + OUTC;                                // 512
    int*   meta   = rowsb + OUTC;                                // 2

    hipMemsetAsync(counts, 0, 8 * sizeof(int), stream);

    dim3 gPX(NPIX / 64, C_ / 64);
    prep_x<<<gPX, 256, 0, stream>>>(x, xp);

    kbucket_kernel<<<OUTC, 64, 0, stream>>>(kern, ah, bh, kbuck);
    gmaps_kernel<<<NPIX / 256, 256, 0, stream>>>(x, ah, g, s2);
    vote_kernel<<<NPIX / 256, 256, 0, stream>>>(g, s2, ah, bh, counts);
    select_kernel<<<1, 1, 0, stream>>>(counts, kbuck, rowsb, meta, out, oc_total);

    prep_w<<<18 * nfTot, 256, 0, stream>>>(kern, rowsb, meta, mode, wfrag, nfTot);

    dim3 gC(NPIX / 64, (nfTot + 8) / 9);
    conv_mfma<<<gC, 64, 0, stream>>>(xp, wfrag, out, nfTot, oc_total);
}

// Round 3
// 257.927 us; speedup vs baseline: 3.6368x; 1.2415x over previous
//
#include <hip/hip_runtime.h>
#include <math.h>

#define N_    16
#define C_    256
#define H_    56
#define W_    56
#define HW_   3136          // H_*W_
#define NPIX  50176         // N_*HW_
#define OUTC  512
#define SPAN_ 2304          // C_*9

typedef unsigned short u16;
typedef unsigned int   u32;
typedef __attribute__((ext_vector_type(8))) short bf16x8;
typedef __attribute__((ext_vector_type(4))) float f32x4;
typedef __attribute__((ext_vector_type(4))) unsigned short u16x4;

__device__ __forceinline__ u16 f2bf(float v) {
    u32 x = __float_as_uint(v);
    u32 r = (x + 0x7fffu + ((x >> 16) & 1u)) >> 16;   // RNE
    return (u16)r;
}

__device__ __forceinline__ int bucketf(float v, float b) {
    int idx = (int)floorf((v + b) / 2.5f);
    int r = idx % 8;
    return r < 0 ? -r : r;
}

// ---- Kernel A: bucket of each kernel row ------------------------------------
__global__ void kbucket_kernel(const float* __restrict__ kern,
                               const float* __restrict__ ah,
                               const float* __restrict__ bh,
                               int* __restrict__ kbuck) {
    int oc = blockIdx.x;
    const float* kr = kern + (size_t)oc * SPAN_;
    float dot = 0.f, ss = 0.f;
    for (int j = threadIdx.x; j < SPAN_; j += 64) {
        float kv = kr[j];
        dot += kv * ah[j];
        ss  += kv * kv;
    }
    for (int o = 32; o; o >>= 1) {
        dot += __shfl_down(dot, o);
        ss  += __shfl_down(ss, o);
    }
    if (threadIdx.x == 0) {
        float n2 = ss;            // ||k||^2
        float n4 = n2 * n2;
        float n8 = n4 * n4;
        float v = dot + n2 * ah[SPAN_] + n4 * ah[SPAN_ + 1] + n8 * ah[SPAN_ + 2];
        kbuck[oc] = bucketf(v, bh[0]);
    }
}

// ---- Kernel B1: channel-reduced tap maps g[9][NPIX] and sumsq map s2[NPIX] --
__global__ __launch_bounds__(256) void gmaps_kernel(const float* __restrict__ x,
                                                    const float* __restrict__ ah,
                                                    float* __restrict__ g,
                                                    float* __restrict__ s2) {
    __shared__ float aL[SPAN_];
    for (int j = threadIdx.x; j < SPAN_; j += 256) aL[j] = ah[j];
    __syncthreads();
    int q = blockIdx.x * 256 + threadIdx.x;
    int n = q / HW_;
    int p = q - n * HW_;
    const float* xb = x + (size_t)n * C_ * HW_ + p;
    float acc[9];
#pragma unroll
    for (int kk = 0; kk < 9; ++kk) acc[kk] = 0.f;
    float ssum = 0.f;
    for (int c = 0; c < C_; ++c) {
        float xv = xb[(size_t)c * HW_];
        ssum += xv * xv;
        const float* ac = &aL[c * 9];
#pragma unroll
        for (int kk = 0; kk < 9; ++kk) acc[kk] += ac[kk] * xv;
    }
#pragma unroll
    for (int kk = 0; kk < 9; ++kk) g[(size_t)kk * NPIX + q] = acc[kk];
    s2[q] = ssum;
}

// ---- Kernel B2: per-column vote -> histogram --------------------------------
__global__ __launch_bounds__(256) void vote_kernel(const float* __restrict__ g,
                                                   const float* __restrict__ s2,
                                                   const float* __restrict__ ah,
                                                   const float* __restrict__ bh,
                                                   int* __restrict__ counts) {
    __shared__ int hist[8];
    if (threadIdx.x < 8) hist[threadIdx.x] = 0;
    __syncthreads();
    int q = blockIdx.x * 256 + threadIdx.x;
    int n = q / HW_;
    int p = q - n * HW_;
    int h = p / W_;
    int w = p - h * W_;
    float dot = 0.f, ss = 0.f;
#pragma unroll
    for (int kk = 0; kk < 9; ++kk) {
        int dh = kk / 3 - 1, dw = kk % 3 - 1;
        int hh = h + dh, ww = w + dw;
        if (hh >= 0 && hh < H_ && ww >= 0 && ww < W_) {
            int idx = n * HW_ + hh * W_ + ww;
            dot += g[(size_t)kk * NPIX + idx];
            ss  += s2[idx];
        }
    }
    float qext = 0.5f * (ah[SPAN_] + ah[SPAN_ + 1] + ah[SPAN_ + 2]);
    float v = dot / sqrtf(ss) + qext;
    int b = bucketf(v, bh[0]);
    atomicAdd(&hist[b], 1);
    __syncthreads();
    if (threadIdx.x < 8) atomicAdd(&counts[threadIdx.x], hist[threadIdx.x]);
}

// ---- Kernel C: argmax bucket + ordered compaction (512-thread scan) ---------
__global__ __launch_bounds__(512) void select_kernel(const int* __restrict__ counts,
                                                     const int* __restrict__ kbuck,
                                                     int* __restrict__ rowsb,
                                                     int* __restrict__ meta,
                                                     float* __restrict__ out,
                                                     int oc_total) {
    __shared__ int sBest;
    __shared__ int sScan[512];
    int t = threadIdx.x;
    if (t == 0) {
        int best = 0, bc = counts[0];
        for (int i = 1; i < 8; ++i) {
            int c = counts[i];
            if (c > bc) { bc = c; best = i; }   // first max wins
        }
        sBest = best;
    }
    __syncthreads();
    int best = sBest;
    int flag = (kbuck[t] == best) ? 1 : 0;
    sScan[t] = flag;
    __syncthreads();
    for (int off = 1; off < 512; off <<= 1) {
        int add = (t >= off) ? sScan[t - off] : 0;
        __syncthreads();
        sScan[t] += add;
        __syncthreads();
    }
    int cnt = sScan[511];
    int pos = sScan[t] - flag;                  // exclusive prefix
    if (flag) rowsb[pos] = t;
    if (cnt == 0) rowsb[t] = t;                 // use-all fallback
    else if (t >= cnt) rowsb[t] = 0;            // safety fill
    if (t == 0) {
        meta[0] = cnt;
        meta[1] = (cnt == 0) ? OUTC : cnt;
    }
    // rows section of d_out (read as f32 by harness)
    float* rout = out + (size_t)N_ * oc_total * HW_;
    int eff = (cnt == 0) ? OUTC : cnt;
    int nw = eff < oc_total ? eff : oc_total;
    if (cnt == 0) {
        if (t < nw) rout[t] = (float)t;
    } else if (flag && pos < nw) {
        rout[pos] = (float)t;
    }
}

// ---- Kernel P1: NCHW f32 -> NHWC bf16 ---------------------------------------
__global__ __launch_bounds__(256) void prep_x(const float* __restrict__ x,
                                              u16* __restrict__ xp) {
    __shared__ u16 tl[64][68];
    int t = threadIdx.x;
    int px0 = blockIdx.x * 64;
    int c0  = blockIdx.y * 64;
    int img = px0 / HW_;
    int hw0 = px0 - img * HW_;
    int px_l = t & 63;
    int cq   = t >> 6;
#pragma unroll
    for (int rep = 0; rep < 16; ++rep) {
        int c_l = rep * 4 + cq;
        float v = x[((size_t)(img * C_ + c0 + c_l)) * HW_ + hw0 + px_l];
        tl[px_l][c_l] = f2bf(v);
    }
    __syncthreads();
    int c4  = t & 15;
    int pxs = t >> 4;
#pragma unroll
    for (int rep = 0; rep < 4; ++rep) {
        int pl = rep * 16 + pxs;
        u16x4 v = *(const u16x4*)(&tl[pl][c4 * 4]);
        *(u16x4*)(&xp[((size_t)(px0 + pl)) * C_ + c0 + c4 * 4]) = v;
    }
}

// ---- Kernel P2: gather active rows -> MFMA B-fragment order bf16 -------------
// wfrag elem offset ((s*nf4 + g)*64 + lane)*8 ; K order = kk*256 + c
__global__ __launch_bounds__(256) void prep_w(const float* __restrict__ kern,
                                              const int* __restrict__ rowsb,
                                              const int* __restrict__ meta,
                                              const int* __restrict__ mode,
                                              u16* __restrict__ wfrag, int nf4) {
    int e = blockIdx.x * 256 + threadIdx.x;
    int lane = e & 63;
    int t2 = e >> 6;
    int g = t2 % nf4;
    int s = t2 / nf4;                    // 0..71
    int kk = s >> 3;
    int cb = s & 7;
    int q = lane >> 4;
    int mcol = lane & 15;
    int ocEff = meta[1];
    int cnt = meta[0];
    float scale = (mode[0] && cnt > 0) ? 512.0f / (float)cnt : 1.0f;
    int oc_i = g * 16 + mcol;
    bool valid = oc_i < ocEff;
    int row = valid ? rowsb[oc_i] : 0;
    const float* kr = kern + (size_t)row * SPAN_;
    u16 w8[8];
#pragma unroll
    for (int j = 0; j < 8; ++j) {
        int c = cb * 32 + q * 8 + j;
        float v = valid ? kr[c * 9 + kk] * scale : 0.f;
        w8[j] = f2bf(v);
    }
    u16* dst = wfrag + ((size_t)((s * nf4 + g) * 64 + lane)) * 8;
#pragma unroll
    for (int j = 0; j < 8; ++j) dst[j] = w8[j];
}

// ---- Kernel D: MFMA implicit-GEMM conv, 4 waves/block -----------------------
// wave tile = 16 px x 64 oc (1 A-frag, 4 B-frags, 4 MFMA per K-step)
__global__ __launch_bounds__(256) void conv_mfma(const u16* __restrict__ xp,
                                                 const u16* __restrict__ wfrag,
                                                 float* __restrict__ out,
                                                 int nf4, int oc_total) {
    const int tid = threadIdx.x;
    const int lane = tid & 63;
    const int wv = tid >> 6;                      // 0..3
    const int pb = blockIdx.x * 64 + wv * 16;
    const int fb = blockIdx.y * 4;

    const int p = pb + (lane & 15);
    const int img = p / HW_;
    const int rp = p - img * HW_;
    const int h = rp / W_;
    const int w = rp - h * W_;
    const u16* xpp = xp + (size_t)p * C_ + ((lane >> 4) * 8);

    f32x4 acc[4];
#pragma unroll
    for (int gg = 0; gg < 4; ++gg) acc[gg] = (f32x4){0.f, 0.f, 0.f, 0.f};
    const bf16x8 zf = {0, 0, 0, 0, 0, 0, 0, 0};

    const size_t kkStride = (size_t)8 * nf4 * 512;   // elems per kk in wfrag
    const u16* wbase = wfrag + (size_t)fb * 512 + (size_t)lane * 8;

#pragma unroll
    for (int kk = 0; kk < 9; ++kk) {
        const int dh = kk / 3 - 1, dw = kk % 3 - 1;
        const int hh = h + dh, ww = w + dw;
        const bool valid = (hh >= 0) & (hh < H_) & (ww >= 0) & (ww < W_);
        const u16* ap = xpp + (dh * W_ + dw) * C_;
        const u16* wkk = wbase + (size_t)kk * kkStride;
#pragma unroll
        for (int cb = 0; cb < 8; ++cb) {
            bf16x8 a = zf;
            if (valid) a = *(const bf16x8*)(ap + cb * 32);
            const u16* wb = wkk + (size_t)cb * nf4 * 512;
#pragma unroll
            for (int gg = 0; gg < 4; ++gg) {
                bf16x8 bW = *(const bf16x8*)(wb + (size_t)gg * 512);
                acc[gg] = __builtin_amdgcn_mfma_f32_16x16x32_bf16(a, bW,
                                                                  acc[gg], 0, 0, 0);
            }
        }
    }

    // epilogue: D row (pixel) = (lane>>4)*4 + r, col (oc) = lane&15
    const int p0 = pb + (lane >> 4) * 4;
    const int img0 = p0 / HW_;
    const int hw0 = p0 - img0 * HW_;
#pragma unroll
    for (int gg = 0; gg < 4; ++gg) {
        int oc = (fb + gg) * 16 + (lane & 15);
        if (oc < oc_total) {
            float* op = out + ((size_t)img0 * oc_total + oc) * HW_ + hw0;
            *(f32x4*)op = acc[gg];
        }
    }
}

extern "C" void kernel_launch(void* const* d_in, const int* in_sizes, int n_in,
                              void* d_out, int out_size, void* d_ws, size_t ws_size,
                              hipStream_t stream) {
    const float* x    = (const float*)d_in[0];
    const float* kern = (const float*)d_in[1];
    const float* ah   = (const float*)d_in[2];
    const float* bh   = (const float*)d_in[3];
    const int*   mode = (const int*)d_in[4];
    float* out = (float*)d_out;

    // oc is data-dependent but recoverable from out_size: oc*(16*3136+1)
    int oc_total = (out_size % (N_ * HW_ + 1) == 0) ? out_size / (N_ * HW_ + 1)
                                                    : OUTC;
    int nfTot = (oc_total + 15) / 16;
    int nf4   = ((nfTot + 3) / 4) * 4;       // pad fragments to multiple of 4

    // workspace layout (sized for worst case nf4 = 32)
    u16*   xp     = (u16*)d_ws;                                  // NPIX*256
    u16*   wfrag  = xp + (size_t)NPIX * C_;                      // 72*32*64*8
    float* g      = (float*)(wfrag + (size_t)72 * 32 * 64 * 8);  // 9*NPIX
    float* s2     = g + (size_t)9 * NPIX;                        // NPIX
    int*   counts = (int*)(s2 + NPIX);                           // 8
    int*   kbuck  = counts + 8;                                  // 512
    int*   rowsb  = kbuck + OUTC;                                // 512
    int*   meta   = rowsb + OUTC;                                // 2

    hipMemsetAsync(counts, 0, 8 * sizeof(int), stream);

    dim3 gPX(NPIX / 64, C_ / 64);
    prep_x<<<gPX, 256, 0, stream>>>(x, xp);

    kbucket_kernel<<<OUTC, 64, 0, stream>>>(kern, ah, bh, kbuck);
    gmaps_kernel<<<NPIX / 256, 256, 0, stream>>>(x, ah, g, s2);
    vote_kernel<<<NPIX / 256, 256, 0, stream>>>(g, s2, ah, bh, counts);
    select_kernel<<<1, 512, 0, stream>>>(counts, kbuck, rowsb, meta, out, oc_total);

    prep_w<<<18 * nf4, 256, 0, stream>>>(kern, rowsb, meta, mode, wfrag, nf4);

    dim3 gC(NPIX / 64, nf4 / 4);
    conv_mfma<<<gC, 256, 0, stream>>>(xp, wfrag, out, nf4, oc_total);
}

// Round 4
// 181.732 us; speedup vs baseline: 5.1616x; 1.4193x over previous
//
#include <hip/hip_runtime.h>
#include <math.h>

#define N_    16
#define C_    256
#define H_    56
#define W_    56
#define HW_   3136          // H_*W_
#define NPIX  50176         // N_*HW_
#define OUTC  512
#define SPAN_ 2304          // C_*9

typedef unsigned short u16;
typedef unsigned int   u32;
typedef __attribute__((ext_vector_type(8))) short bf16x8;
typedef __attribute__((ext_vector_type(4))) float f32x4;
typedef __attribute__((ext_vector_type(4))) unsigned short u16x4;

__device__ __forceinline__ u16 f2bf(float v) {
    u32 x = __float_as_uint(v);
    u32 r = (x + 0x7fffu + ((x >> 16) & 1u)) >> 16;   // RNE
    return (u16)r;
}

__device__ __forceinline__ int bucketf(float v, float b) {
    int idx = (int)floorf((v + b) / 2.5f);
    int r = idx % 8;
    return r < 0 ? -r : r;
}

// ---- Kernel A: bucket of each kernel row ------------------------------------
__global__ void kbucket_kernel(const float* __restrict__ kern,
                               const float* __restrict__ ah,
                               const float* __restrict__ bh,
                               int* __restrict__ kbuck) {
    int oc = blockIdx.x;
    const float* kr = kern + (size_t)oc * SPAN_;
    float dot = 0.f, ss = 0.f;
    for (int j = threadIdx.x; j < SPAN_; j += 64) {
        float kv = kr[j];
        dot += kv * ah[j];
        ss  += kv * kv;
    }
    for (int o = 32; o; o >>= 1) {
        dot += __shfl_down(dot, o);
        ss  += __shfl_down(ss, o);
    }
    if (threadIdx.x == 0) {
        float n2 = ss;            // ||k||^2
        float n4 = n2 * n2;
        float n8 = n4 * n4;
        float v = dot + n2 * ah[SPAN_] + n4 * ah[SPAN_ + 1] + n8 * ah[SPAN_ + 2];
        kbuck[oc] = bucketf(v, bh[0]);
    }
}

// ---- Kernel P1+B1 fused: NCHW f32 -> NHWC bf16, tap maps g[9], sumsq s2 -----
// grid NPIX/64, block 256 (4 channel-groups x 64 px)
__global__ __launch_bounds__(256) void prep_fused(const float* __restrict__ x,
                                                  const float* __restrict__ ah,
                                                  u16* __restrict__ xp,
                                                  float* __restrict__ g,
                                                  float* __restrict__ s2) {
    __shared__ float aL[SPAN_];          // 9216 B
    __shared__ u16 tl[64][68];           // 8704 B
    __shared__ float red[4][64][10];     // 10240 B
    int t = threadIdx.x;
    for (int j = t; j < SPAN_; j += 256) aL[j] = ah[j];

    int px0 = blockIdx.x * 64;
    int img = px0 / HW_;
    int hw0 = px0 - img * HW_;
    int px_l = t & 63;
    int cq   = t >> 6;                   // 0..3
    float pg[9];
#pragma unroll
    for (int kk = 0; kk < 9; ++kk) pg[kk] = 0.f;
    float ps = 0.f;
    __syncthreads();

    for (int cb0 = 0; cb0 < 4; ++cb0) {
        int c0 = cb0 * 64;
#pragma unroll
        for (int rep = 0; rep < 16; ++rep) {
            int c_l = rep * 4 + cq;
            float v = x[((size_t)(img * C_ + c0 + c_l)) * HW_ + hw0 + px_l];
            tl[px_l][c_l] = f2bf(v);
            const float* ac = &aL[(c0 + c_l) * 9];
#pragma unroll
            for (int kk = 0; kk < 9; ++kk) pg[kk] += ac[kk] * v;
            ps += v * v;
        }
        __syncthreads();
        int c4  = t & 15;
        int pxs = t >> 4;
#pragma unroll
        for (int rep = 0; rep < 4; ++rep) {
            int pl = rep * 16 + pxs;
            u16x4 v4 = *(const u16x4*)(&tl[pl][c4 * 4]);
            *(u16x4*)(&xp[((size_t)(px0 + pl)) * C_ + c0 + c4 * 4]) = v4;
        }
        __syncthreads();
    }

#pragma unroll
    for (int kk = 0; kk < 9; ++kk) red[cq][px_l][kk] = pg[kk];
    red[cq][px_l][9] = ps;
    __syncthreads();
    for (int it = t; it < 640; it += 256) {
        int pl = it / 10;
        int j  = it - pl * 10;
        float s = red[0][pl][j] + red[1][pl][j] + red[2][pl][j] + red[3][pl][j];
        int q = px0 + pl;
        if (j < 9) g[(size_t)j * NPIX + q] = s;
        else       s2[q] = s;
    }
}

// ---- Kernel B2: per-column vote -> histogram --------------------------------
__global__ __launch_bounds__(256) void vote_kernel(const float* __restrict__ g,
                                                   const float* __restrict__ s2,
                                                   const float* __restrict__ ah,
                                                   const float* __restrict__ bh,
                                                   int* __restrict__ counts) {
    __shared__ int hist[8];
    if (threadIdx.x < 8) hist[threadIdx.x] = 0;
    __syncthreads();
    int q = blockIdx.x * 256 + threadIdx.x;
    int n = q / HW_;
    int p = q - n * HW_;
    int h = p / W_;
    int w = p - h * W_;
    float dot = 0.f, ss = 0.f;
#pragma unroll
    for (int kk = 0; kk < 9; ++kk) {
        int dh = kk / 3 - 1, dw = kk % 3 - 1;
        int hh = h + dh, ww = w + dw;
        if (hh >= 0 && hh < H_ && ww >= 0 && ww < W_) {
            int idx = n * HW_ + hh * W_ + ww;
            dot += g[(size_t)kk * NPIX + idx];
            ss  += s2[idx];
        }
    }
    float qext = 0.5f * (ah[SPAN_] + ah[SPAN_ + 1] + ah[SPAN_ + 2]);
    float v = dot / sqrtf(ss) + qext;
    int b = bucketf(v, bh[0]);
    atomicAdd(&hist[b], 1);
    __syncthreads();
    if (threadIdx.x < 8) atomicAdd(&counts[threadIdx.x], hist[threadIdx.x]);
}

// ---- Kernel C: argmax bucket + ordered compaction (512-thread scan) ---------
__global__ __launch_bounds__(512) void select_kernel(const int* __restrict__ counts,
                                                     const int* __restrict__ kbuck,
                                                     int* __restrict__ rowsb,
                                                     int* __restrict__ meta,
                                                     float* __restrict__ out,
                                                     int oc_total) {
    __shared__ int sBest;
    __shared__ int sScan[512];
    int t = threadIdx.x;
    if (t == 0) {
        int best = 0, bc = counts[0];
        for (int i = 1; i < 8; ++i) {
            int c = counts[i];
            if (c > bc) { bc = c; best = i; }   // first max wins
        }
        sBest = best;
    }
    __syncthreads();
    int best = sBest;
    int flag = (kbuck[t] == best) ? 1 : 0;
    sScan[t] = flag;
    __syncthreads();
    for (int off = 1; off < 512; off <<= 1) {
        int add = (t >= off) ? sScan[t - off] : 0;
        __syncthreads();
        sScan[t] += add;
        __syncthreads();
    }
    int cnt = sScan[511];
    int pos = sScan[t] - flag;                  // exclusive prefix
    if (flag) rowsb[pos] = t;
    if (cnt == 0) rowsb[t] = t;                 // use-all fallback
    else if (t >= cnt) rowsb[t] = 0;            // safety fill
    if (t == 0) {
        meta[0] = cnt;
        meta[1] = (cnt == 0) ? OUTC : cnt;
    }
    float* rout = out + (size_t)N_ * oc_total * HW_;
    int eff = (cnt == 0) ? OUTC : cnt;
    int nw = eff < oc_total ? eff : oc_total;
    if (cnt == 0) {
        if (t < nw) rout[t] = (float)t;
    } else if (flag && pos < nw) {
        rout[pos] = (float)t;
    }
}

// ---- Kernel P2: gather active rows -> MFMA B-fragment order bf16 -------------
// wfrag elem offset ((s*nf4 + g)*64 + lane)*8 ; K order = kk*256 + c
__global__ __launch_bounds__(256) void prep_w(const float* __restrict__ kern,
                                              const int* __restrict__ rowsb,
                                              const int* __restrict__ meta,
                                              const int* __restrict__ mode,
                                              u16* __restrict__ wfrag, int nf4) {
    int e = blockIdx.x * 256 + threadIdx.x;
    int lane = e & 63;
    int t2 = e >> 6;
    int g = t2 % nf4;
    int s = t2 / nf4;                    // 0..71
    int kk = s >> 3;
    int cb = s & 7;
    int q = lane >> 4;
    int mcol = lane & 15;
    int ocEff = meta[1];
    int cnt = meta[0];
    float scale = (mode[0] && cnt > 0) ? 512.0f / (float)cnt : 1.0f;
    int oc_i = g * 16 + mcol;
    bool valid = oc_i < ocEff;
    int row = valid ? rowsb[oc_i] : 0;
    const float* kr = kern + (size_t)row * SPAN_;
    u16 w8[8];
#pragma unroll
    for (int j = 0; j < 8; ++j) {
        int c = cb * 32 + q * 8 + j;
        float v = valid ? kr[c * 9 + kk] * scale : 0.f;
        w8[j] = f2bf(v);
    }
    u16* dst = wfrag + ((size_t)((s * nf4 + g) * 64 + lane)) * 8;
#pragma unroll
    for (int j = 0; j < 8; ++j) dst[j] = w8[j];
}

// ---- Kernel D: MFMA implicit-GEMM conv --------------------------------------
// 4 waves/block; wave tile = 64 px x 64 oc (4 A-frags x 4 B-frags, 16 MFMA/step)
__global__ __launch_bounds__(256, 2) void conv_mfma(const u16* __restrict__ xp,
                                                    const u16* __restrict__ wfrag,
                                                    float* __restrict__ out,
                                                    int nf4, int oc_total) {
    const int tid = threadIdx.x;
    const int lane = tid & 63;
    const int wv = tid >> 6;                      // 0..3
    const int pbw = blockIdx.x * 256 + wv * 64;   // wave's 64-px base
    const int fb = blockIdx.y * 4;

    int hA[4], wA[4];
    const u16* xpf[4];
#pragma unroll
    for (int f = 0; f < 4; ++f) {
        int p = pbw + f * 16 + (lane & 15);
        int img = p / HW_;
        int rp = p - img * HW_;
        hA[f] = rp / W_;
        wA[f] = rp - hA[f] * W_;
        xpf[f] = xp + (size_t)p * C_ + ((lane >> 4) * 8);
    }

    f32x4 acc[4][4];
#pragma unroll
    for (int f = 0; f < 4; ++f)
#pragma unroll
        for (int gg = 0; gg < 4; ++gg) acc[f][gg] = (f32x4){0.f, 0.f, 0.f, 0.f};
    const bf16x8 zf = {0, 0, 0, 0, 0, 0, 0, 0};

    const size_t nfStride = (size_t)nf4 * 512;    // elems per s-step

    for (int kk = 0; kk < 9; ++kk) {
        const int dh = kk / 3 - 1, dw = kk % 3 - 1;
        const int offp = (dh * W_ + dw) * C_;
        bool val[4];
#pragma unroll
        for (int f = 0; f < 4; ++f) {
            int hh = hA[f] + dh, ww = wA[f] + dw;
            val[f] = (hh >= 0) & (hh < H_) & (ww >= 0) & (ww < W_);
        }
        const u16* wkk = wfrag + ((size_t)(kk * 8) * nf4 + fb) * 512 + lane * 8;
#pragma unroll
        for (int cb = 0; cb < 8; ++cb) {
            bf16x8 aX[4];
#pragma unroll
            for (int f = 0; f < 4; ++f) {
                bf16x8 a = zf;
                if (val[f]) a = *(const bf16x8*)(xpf[f] + offp + cb * 32);
                aX[f] = a;
            }
            const u16* wb = wkk + (size_t)cb * nfStride;
            bf16x8 bW[4];
#pragma unroll
            for (int gg = 0; gg < 4; ++gg)
                bW[gg] = *(const bf16x8*)(wb + (size_t)gg * 512);
#pragma unroll
            for (int gg = 0; gg < 4; ++gg)
#pragma unroll
                for (int f = 0; f < 4; ++f)
                    acc[f][gg] = __builtin_amdgcn_mfma_f32_16x16x32_bf16(
                        aX[f], bW[gg], acc[f][gg], 0, 0, 0);
        }
    }

    // epilogue: D row (pixel) = (lane>>4)*4 + r, col (oc) = lane&15
#pragma unroll
    for (int f = 0; f < 4; ++f) {
        int p0 = pbw + f * 16 + (lane >> 4) * 4;
        int img0 = p0 / HW_;
        int hw0 = p0 - img0 * HW_;
#pragma unroll
        for (int gg = 0; gg < 4; ++gg) {
            int oc = (fb + gg) * 16 + (lane & 15);
            if (oc < oc_total) {
                float* op = out + ((size_t)img0 * oc_total + oc) * HW_ + hw0;
                *(f32x4*)op = acc[f][gg];
            }
        }
    }
}

extern "C" void kernel_launch(void* const* d_in, const int* in_sizes, int n_in,
                              void* d_out, int out_size, void* d_ws, size_t ws_size,
                              hipStream_t stream) {
    const float* x    = (const float*)d_in[0];
    const float* kern = (const float*)d_in[1];
    const float* ah   = (const float*)d_in[2];
    const float* bh   = (const float*)d_in[3];
    const int*   mode = (const int*)d_in[4];
    float* out = (float*)d_out;

    // oc is data-dependent but recoverable from out_size: oc*(16*3136+1)
    int oc_total = (out_size % (N_ * HW_ + 1) == 0) ? out_size / (N_ * HW_ + 1)
                                                    : OUTC;
    int nfTot = (oc_total + 15) / 16;
    int nf4   = ((nfTot + 3) / 4) * 4;       // pad fragments to multiple of 4

    // workspace layout (sized for worst case nf4 = 32)
    u16*   xp     = (u16*)d_ws;                                  // NPIX*256
    u16*   wfrag  = xp + (size_t)NPIX * C_;                      // 72*32*64*8
    float* g      = (float*)(wfrag + (size_t)72 * 32 * 64 * 8);  // 9*NPIX
    float* s2     = g + (size_t)9 * NPIX;                        // NPIX
    int*   counts = (int*)(s2 + NPIX);                           // 8
    int*   kbuck  = counts + 8;                                  // 512
    int*   rowsb  = kbuck + OUTC;                                // 512
    int*   meta   = rowsb + OUTC;                                // 2

    hipMemsetAsync(counts, 0, 8 * sizeof(int), stream);

    prep_fused<<<NPIX / 64, 256, 0, stream>>>(x, ah, xp, g, s2);

    kbucket_kernel<<<OUTC, 64, 0, stream>>>(kern, ah, bh, kbuck);
    vote_kernel<<<NPIX / 256, 256, 0, stream>>>(g, s2, ah, bh, counts);
    select_kernel<<<1, 512, 0, stream>>>(counts, kbuck, rowsb, meta, out, oc_total);

    prep_w<<<18 * nf4, 256, 0, stream>>>(kern, rowsb, meta, mode, wfrag, nf4);

    dim3 gC(NPIX / 256, nf4 / 4);
    conv_mfma<<<gC, 256, 0, stream>>>(xp, wfrag, out, nf4, oc_total);
}

// Round 5
// 111.229 us; speedup vs baseline: 8.4334x; 1.6339x over previous
//
#include <hip/hip_runtime.h>
#include <math.h>

#define N_    16
#define C_    256
#define H_    56
#define W_    56
#define HW_   3136          // H_*W_
#define NPIX  50176         // N_*HW_
#define OUTC  512
#define SPAN_ 2304          // C_*9
#define BLKPX 256           // conv block pixel tile
#define HSLOT 384           // halo pixel slots (>= 256 + 114)

typedef unsigned short u16;
typedef unsigned int   u32;
typedef __attribute__((ext_vector_type(8))) short bf16x8;
typedef __attribute__((ext_vector_type(8))) unsigned short u16x8;
typedef __attribute__((ext_vector_type(4))) float f32x4;
typedef __attribute__((ext_vector_type(4))) unsigned short u16x4;

__device__ __forceinline__ u16 f2bf(float v) {
    u32 x = __float_as_uint(v);
    u32 r = (x + 0x7fffu + ((x >> 16) & 1u)) >> 16;   // RNE
    return (u16)r;
}

__device__ __forceinline__ int bucketf(float v, float b) {
    int idx = (int)floorf((v + b) / 2.5f);
    int r = idx % 8;
    return r < 0 ? -r : r;
}

// ---- Kernel A: bucket of each kernel row ------------------------------------
__global__ void kbucket_kernel(const float* __restrict__ kern,
                               const float* __restrict__ ah,
                               const float* __restrict__ bh,
                               int* __restrict__ kbuck) {
    int oc = blockIdx.x;
    const float* kr = kern + (size_t)oc * SPAN_;
    float dot = 0.f, ss = 0.f;
    for (int j = threadIdx.x; j < SPAN_; j += 64) {
        float kv = kr[j];
        dot += kv * ah[j];
        ss  += kv * kv;
    }
    for (int o = 32; o; o >>= 1) {
        dot += __shfl_down(dot, o);
        ss  += __shfl_down(ss, o);
    }
    if (threadIdx.x == 0) {
        float n2 = ss;            // ||k||^2
        float n4 = n2 * n2;
        float n8 = n4 * n4;
        float v = dot + n2 * ah[SPAN_] + n4 * ah[SPAN_ + 1] + n8 * ah[SPAN_ + 2];
        kbuck[oc] = bucketf(v, bh[0]);
    }
}

// ---- Kernel P1+B1 fused: NCHW f32 -> NHWC bf16, tap maps g[9], sumsq s2 -----
__global__ __launch_bounds__(256) void prep_fused(const float* __restrict__ x,
                                                  const float* __restrict__ ah,
                                                  u16* __restrict__ xp,
                                                  float* __restrict__ g,
                                                  float* __restrict__ s2) {
    __shared__ float aL[SPAN_];          // 9216 B
    __shared__ u16 tl[64][68];           // 8704 B
    __shared__ float red[4][64][10];     // 10240 B
    int t = threadIdx.x;
    for (int j = t; j < SPAN_; j += 256) aL[j] = ah[j];

    int px0 = blockIdx.x * 64;
    int img = px0 / HW_;
    int hw0 = px0 - img * HW_;
    int px_l = t & 63;
    int cq   = t >> 6;                   // 0..3
    float pg[9];
#pragma unroll
    for (int kk = 0; kk < 9; ++kk) pg[kk] = 0.f;
    float ps = 0.f;
    __syncthreads();

    for (int cb0 = 0; cb0 < 4; ++cb0) {
        int c0 = cb0 * 64;
#pragma unroll
        for (int rep = 0; rep < 16; ++rep) {
            int c_l = rep * 4 + cq;
            float v = x[((size_t)(img * C_ + c0 + c_l)) * HW_ + hw0 + px_l];
            tl[px_l][c_l] = f2bf(v);
            const float* ac = &aL[(c0 + c_l) * 9];
#pragma unroll
            for (int kk = 0; kk < 9; ++kk) pg[kk] += ac[kk] * v;
            ps += v * v;
        }
        __syncthreads();
        int c4  = t & 15;
        int pxs = t >> 4;
#pragma unroll
        for (int rep = 0; rep < 4; ++rep) {
            int pl = rep * 16 + pxs;
            u16x4 v4 = *(const u16x4*)(&tl[pl][c4 * 4]);
            *(u16x4*)(&xp[((size_t)(px0 + pl)) * C_ + c0 + c4 * 4]) = v4;
        }
        __syncthreads();
    }

#pragma unroll
    for (int kk = 0; kk < 9; ++kk) red[cq][px_l][kk] = pg[kk];
    red[cq][px_l][9] = ps;
    __syncthreads();
    for (int it = t; it < 640; it += 256) {
        int pl = it / 10;
        int j  = it - pl * 10;
        float s = red[0][pl][j] + red[1][pl][j] + red[2][pl][j] + red[3][pl][j];
        int q = px0 + pl;
        if (j < 9) g[(size_t)j * NPIX + q] = s;
        else       s2[q] = s;
    }
}

// ---- Kernel B2: per-column vote -> histogram --------------------------------
__global__ __launch_bounds__(256) void vote_kernel(const float* __restrict__ g,
                                                   const float* __restrict__ s2,
                                                   const float* __restrict__ ah,
                                                   const float* __restrict__ bh,
                                                   int* __restrict__ counts) {
    __shared__ int hist[8];
    if (threadIdx.x < 8) hist[threadIdx.x] = 0;
    __syncthreads();
    int q = blockIdx.x * 256 + threadIdx.x;
    int n = q / HW_;
    int p = q - n * HW_;
    int h = p / W_;
    int w = p - h * W_;
    float dot = 0.f, ss = 0.f;
#pragma unroll
    for (int kk = 0; kk < 9; ++kk) {
        int dh = kk / 3 - 1, dw = kk % 3 - 1;
        int hh = h + dh, ww = w + dw;
        if (hh >= 0 && hh < H_ && ww >= 0 && ww < W_) {
            int idx = n * HW_ + hh * W_ + ww;
            dot += g[(size_t)kk * NPIX + idx];
            ss  += s2[idx];
        }
    }
    float qext = 0.5f * (ah[SPAN_] + ah[SPAN_ + 1] + ah[SPAN_ + 2]);
    float v = dot / sqrtf(ss) + qext;
    int b = bucketf(v, bh[0]);
    atomicAdd(&hist[b], 1);
    __syncthreads();
    if (threadIdx.x < 8) atomicAdd(&counts[threadIdx.x], hist[threadIdx.x]);
}

// ---- Kernel C: argmax bucket + ordered compaction (512-thread scan) ---------
__global__ __launch_bounds__(512) void select_kernel(const int* __restrict__ counts,
                                                     const int* __restrict__ kbuck,
                                                     int* __restrict__ rowsb,
                                                     int* __restrict__ meta,
                                                     float* __restrict__ out,
                                                     int oc_total) {
    __shared__ int sBest;
    __shared__ int sScan[512];
    int t = threadIdx.x;
    if (t == 0) {
        int best = 0, bc = counts[0];
        for (int i = 1; i < 8; ++i) {
            int c = counts[i];
            if (c > bc) { bc = c; best = i; }   // first max wins
        }
        sBest = best;
    }
    __syncthreads();
    int best = sBest;
    int flag = (kbuck[t] == best) ? 1 : 0;
    sScan[t] = flag;
    __syncthreads();
    for (int off = 1; off < 512; off <<= 1) {
        int add = (t >= off) ? sScan[t - off] : 0;
        __syncthreads();
        sScan[t] += add;
        __syncthreads();
    }
    int cnt = sScan[511];
    int pos = sScan[t] - flag;                  // exclusive prefix
    if (flag) rowsb[pos] = t;
    if (cnt == 0) rowsb[t] = t;                 // use-all fallback
    else if (t >= cnt) rowsb[t] = 0;            // safety fill
    if (t == 0) {
        meta[0] = cnt;
        meta[1] = (cnt == 0) ? OUTC : cnt;
    }
    float* rout = out + (size_t)N_ * oc_total * HW_;
    int eff = (cnt == 0) ? OUTC : cnt;
    int nw = eff < oc_total ? eff : oc_total;
    if (cnt == 0) {
        if (t < nw) rout[t] = (float)t;
    } else if (flag && pos < nw) {
        rout[pos] = (float)t;
    }
}

// ---- Kernel P2: gather active rows -> MFMA B-fragment order bf16 -------------
__global__ __launch_bounds__(256) void prep_w(const float* __restrict__ kern,
                                              const int* __restrict__ rowsb,
                                              const int* __restrict__ meta,
                                              const int* __restrict__ mode,
                                              u16* __restrict__ wfrag, int nf4) {
    int e = blockIdx.x * 256 + threadIdx.x;
    int lane = e & 63;
    int t2 = e >> 6;
    int g = t2 % nf4;
    int s = t2 / nf4;                    // 0..71
    int kk = s >> 3;
    int cb = s & 7;
    int q = lane >> 4;
    int mcol = lane & 15;
    int ocEff = meta[1];
    int cnt = meta[0];
    float scale = (mode[0] && cnt > 0) ? 512.0f / (float)cnt : 1.0f;
    int oc_i = g * 16 + mcol;
    bool valid = oc_i < ocEff;
    int row = valid ? rowsb[oc_i] : 0;
    const float* kr = kern + (size_t)row * SPAN_;
    u16 w8[8];
#pragma unroll
    for (int j = 0; j < 8; ++j) {
        int c = cb * 32 + q * 8 + j;
        float v = valid ? kr[c * 9 + kk] * scale : 0.f;
        w8[j] = f2bf(v);
    }
    u16* dst = wfrag + ((size_t)((s * nf4 + g) * 64 + lane)) * 8;
#pragma unroll
    for (int j = 0; j < 8; ++j) dst[j] = w8[j];
}

// ---- Kernel D: MFMA implicit-GEMM conv with LDS halo staging ----------------
// block = 256 threads (4 waves); block tile = 256 px x 64 oc; per 32-ch step
// stage the halo pixel window into LDS once, read all 9 taps from LDS.
__global__ __launch_bounds__(256, 2) void conv_mfma(const u16* __restrict__ xp,
                                                    const u16* __restrict__ wfrag,
                                                    float* __restrict__ out,
                                                    int nf4, int oc_total, int nby) {
    __shared__ u16 halo[HSLOT * 32];               // 24576 B

    // XCD swizzle: oc-sibling blocks (same bx, by=0..nby-1) get dispatch ids
    // differing by 8 -> same XCD L2 -> shared A halo.  196 bx = 24*8 + 4.
    int flat = blockIdx.x;
    int bx, by;
    int full = 192 * nby;
    if (flat < full) {
        int gsz = 8 * nby;
        int gi = flat / gsz;
        int tr = flat - gi * gsz;
        by = tr >> 3;
        bx = gi * 8 + (tr & 7);
    } else {
        int tr = flat - full;
        by = tr >> 2;
        bx = 192 + (tr & 3);
    }

    const int t = threadIdx.x;
    const int lane = t & 63;
    const int wv = t >> 6;                         // 0..3
    const int pb = bx * BLKPX;
    const int fb = by * 4;
    const int lane15 = lane & 15;
    const int laneq  = lane >> 4;

    // per-fragment pixel coords + LDS base indices
    int hA[4], wA[4], aBase[4];
#pragma unroll
    for (int f = 0; f < 4; ++f) {
        int p = pb + wv * 64 + f * 16 + lane15;
        int img = p / HW_;
        int rp = p - img * HW_;
        hA[f] = rp / W_;
        wA[f] = rp - hA[f] * W_;
        aBase[f] = (wv * 64 + f * 16 + 57 + lane15) * 32 + laneq * 8;
    }

    f32x4 acc[4][4];
#pragma unroll
    for (int f = 0; f < 4; ++f)
#pragma unroll
        for (int gg = 0; gg < 4; ++gg) acc[f][gg] = (f32x4){0.f, 0.f, 0.f, 0.f};
    const bf16x8 zf = {0, 0, 0, 0, 0, 0, 0, 0};

    const int plb = t >> 2;                        // staging px sub-index
    const int cby = (t & 3) * 16;                  // staging byte-in-slot
    const char* xpb = (const char*)xp;

    // preload staging regs for cb = 0
    u16x8 R[6], R2[6];
#pragma unroll
    for (int r = 0; r < 6; ++r) {
        int gpx = pb - 57 + r * 64 + plb;
        gpx = gpx < 0 ? 0 : (gpx >= NPIX ? NPIX - 1 : gpx);
        R[r] = *(const u16x8*)(xpb + (size_t)gpx * 512 + cby);
    }

    const size_t kkStride = (size_t)8 * nf4 * 512;

    for (int cb = 0; cb < 8; ++cb) {
        __syncthreads();                           // halo free to overwrite
#pragma unroll
        for (int r = 0; r < 6; ++r)
            *(u16x8*)&halo[r * 2048 + t * 8] = R[r];
        __syncthreads();                           // halo[cb] ready

        if (cb < 7) {
#pragma unroll
            for (int r = 0; r < 6; ++r) {
                int gpx = pb - 57 + r * 64 + plb;
                gpx = gpx < 0 ? 0 : (gpx >= NPIX ? NPIX - 1 : gpx);
                R2[r] = *(const u16x8*)(xpb + (size_t)gpx * 512 +
                                        (cb + 1) * 64 + cby);
            }
        }

        const u16* wcb = wfrag + ((size_t)cb * nf4 + fb) * 512 + lane * 8;
#pragma unroll
        for (int kk = 0; kk < 9; ++kk) {
            const int dh = kk / 3 - 1, dw = kk % 3 - 1;
            const int toff32 = (dh * W_ + dw) * 32;
            bf16x8 aX[4];
#pragma unroll
            for (int f = 0; f < 4; ++f) {
                int hh = hA[f] + dh, ww = wA[f] + dw;
                bool val = (hh >= 0) & (hh < H_) & (ww >= 0) & (ww < W_);
                bf16x8 a = *(const bf16x8*)&halo[aBase[f] + toff32];
                aX[f] = val ? a : zf;
            }
            const u16* wk = wcb + (size_t)kk * kkStride;
            bf16x8 bW[4];
#pragma unroll
            for (int gg = 0; gg < 4; ++gg)
                bW[gg] = *(const bf16x8*)(wk + (size_t)gg * 512);
#pragma unroll
            for (int gg = 0; gg < 4; ++gg)
#pragma unroll
                for (int f = 0; f < 4; ++f)
                    acc[f][gg] = __builtin_amdgcn_mfma_f32_16x16x32_bf16(
                        aX[f], bW[gg], acc[f][gg], 0, 0, 0);
        }
#pragma unroll
        for (int r = 0; r < 6; ++r) R[r] = R2[r];
    }

    // epilogue: D row (pixel) = (lane>>4)*4 + r, col (oc) = lane&15
#pragma unroll
    for (int f = 0; f < 4; ++f) {
        int p0 = pb + wv * 64 + f * 16 + laneq * 4;
        int img0 = p0 / HW_;
        int hw0 = p0 - img0 * HW_;
#pragma unroll
        for (int gg = 0; gg < 4; ++gg) {
            int oc = (fb + gg) * 16 + lane15;
            if (oc < oc_total) {
                float* op = out + ((size_t)img0 * oc_total + oc) * HW_ + hw0;
                *(f32x4*)op = acc[f][gg];
            }
        }
    }
}

extern "C" void kernel_launch(void* const* d_in, const int* in_sizes, int n_in,
                              void* d_out, int out_size, void* d_ws, size_t ws_size,
                              hipStream_t stream) {
    const float* x    = (const float*)d_in[0];
    const float* kern = (const float*)d_in[1];
    const float* ah   = (const float*)d_in[2];
    const float* bh   = (const float*)d_in[3];
    const int*   mode = (const int*)d_in[4];
    float* out = (float*)d_out;

    // oc is data-dependent but recoverable from out_size: oc*(16*3136+1)
    int oc_total = (out_size % (N_ * HW_ + 1) == 0) ? out_size / (N_ * HW_ + 1)
                                                    : OUTC;
    int nfTot = (oc_total + 15) / 16;
    int nf4   = ((nfTot + 3) / 4) * 4;       // pad fragments to multiple of 4
    int nby   = nf4 / 4;

    // workspace layout (sized for worst case nf4 = 32)
    u16*   xp     = (u16*)d_ws;                                  // NPIX*256
    u16*   wfrag  = xp + (size_t)NPIX * C_;                      // 72*32*64*8
    float* g      = (float*)(wfrag + (size_t)72 * 32 * 64 * 8);  // 9*NPIX
    float* s2     = g + (size_t)9 * NPIX;                        // NPIX
    int*   counts = (int*)(s2 + NPIX);                           // 8
    int*   kbuck  = counts + 8;                                  // 512
    int*   rowsb  = kbuck + OUTC;                                // 512
    int*   meta   = rowsb + OUTC;                                // 2

    hipMemsetAsync(counts, 0, 8 * sizeof(int), stream);

    prep_fused<<<NPIX / 64, 256, 0, stream>>>(x, ah, xp, g, s2);

    kbucket_kernel<<<OUTC, 64, 0, stream>>>(kern, ah, bh, kbuck);
    vote_kernel<<<NPIX / 256, 256, 0, stream>>>(g, s2, ah, bh, counts);
    select_kernel<<<1, 512, 0, stream>>>(counts, kbuck, rowsb, meta, out, oc_total);

    prep_w<<<18 * nf4, 256, 0, stream>>>(kern, rowsb, meta, mode, wfrag, nf4);

    conv_mfma<<<(NPIX / BLKPX) * nby, 256, 0, stream>>>(xp, wfrag, out, nf4,
                                                        oc_total, nby);
}